// Round 2
// 932.210 us; speedup vs baseline: 1.0323x; 1.0323x over previous
//
#include <hip/hip_runtime.h>
#include <math.h>

typedef __attribute__((ext_vector_type(8))) short short8;
typedef __attribute__((ext_vector_type(4))) float f32x4;

static __device__ __forceinline__ unsigned short f2bf(float f) {
    unsigned int u = __float_as_uint(f);
    unsigned int r = (u + 0x7FFFu + ((u >> 16) & 1u)) >> 16;
    return (unsigned short)r;
}
static __device__ __forceinline__ float b2f(unsigned short s) {
    return __uint_as_float(((unsigned int)s) << 16);
}
static __device__ __forceinline__ float blo(unsigned int u) { return __uint_as_float(u << 16); }
static __device__ __forceinline__ float bhi(unsigned int u) { return __uint_as_float(u & 0xFFFF0000u); }

// ---------------- graph build ----------------

__global__ void count_kernel(const int* __restrict__ ei, int* __restrict__ cnt, int E) {
    int e = blockIdx.x * 256 + threadIdx.x;
    if (e < E) atomicAdd(&cnt[ei[E + e]], 1);
}

__global__ void scanA_kernel(const int* __restrict__ cnt, float* __restrict__ dinv,
                             int* __restrict__ colptr, int* __restrict__ bsum, int n) {
    __shared__ int s[256];
    int b = blockIdx.x, t = threadIdx.x;
    int i = b * 512 + 2 * t;
    int c0 = (i     < n) ? cnt[i]     : 0;
    int c1 = (i + 1 < n) ? cnt[i + 1] : 0;
    if (i     < n) dinv[i]     = rsqrtf((float)(c0 + 1));
    if (i + 1 < n) dinv[i + 1] = rsqrtf((float)(c1 + 1));
    int v = c0 + c1;
    s[t] = v;
    __syncthreads();
    #pragma unroll
    for (int o = 1; o < 256; o <<= 1) {
        int x = (t >= o) ? s[t - o] : 0;
        __syncthreads();
        s[t] += x;
        __syncthreads();
    }
    int excl = s[t] - v;
    if (i     < n) colptr[i]     = excl;
    if (i + 1 < n) colptr[i + 1] = excl + c0;
    if (t == 255) bsum[b] = s[t];
}

__global__ void scanB_kernel(int* bsum, int nb) {
    __shared__ int s[256];
    int t = threadIdx.x;
    int v = (t < nb) ? bsum[t] : 0;
    s[t] = v;
    __syncthreads();
    #pragma unroll
    for (int o = 1; o < 256; o <<= 1) {
        int x = (t >= o) ? s[t - o] : 0;
        __syncthreads();
        s[t] += x;
        __syncthreads();
    }
    if (t < nb) bsum[t] = s[t] - v;
}

__global__ void scanC_kernel(int* __restrict__ colptr, const int* __restrict__ bsum,
                             int n, int E) {
    int b = blockIdx.x, t = threadIdx.x;
    int off = bsum[b];
    int i = b * 512 + 2 * t;
    if (i     < n) colptr[i]     += off;
    if (i + 1 < n) colptr[i + 1] += off;
    if (b == 0 && t == 0) colptr[n] = E;
}

__global__ void fill_kernel(const int* __restrict__ ei, const int* __restrict__ colptr,
                            int* __restrict__ fillc, int* __restrict__ eidx, int E) {
    int e = blockIdx.x * 256 + threadIdx.x;
    if (e < E) {
        int r = ei[e];
        int c = ei[E + e];
        int pos = colptr[c] + atomicAdd(&fillc[c], 1);
        eidx[pos] = r;
    }
}

// W1 [512][256] -> w1t [256][512] bf16 ; W2 [256][40] -> w2t [64][256] bf16 (pad 0)
__global__ void prep_w_kernel(const float* __restrict__ W1, const float* __restrict__ W2,
                              unsigned short* __restrict__ w1t, unsigned short* __restrict__ w2t) {
    int id = blockIdx.x * 256 + threadIdx.x;
    if (id < 512 * 256) {
        int k = id >> 8, n = id & 255;
        w1t[(size_t)n * 512 + k] = f2bf(W1[id]);
    } else {
        int id2 = id - 512 * 256;
        if (id2 < 64 * 256) {
            int n = id2 >> 8, k = id2 & 255;
            w2t[id2] = (n < 40) ? f2bf(W2[k * 40 + n]) : (unsigned short)0;
        }
    }
}

// ---------------- layer 1 GEMM (bf16 MFMA, fused fp32->bf16, double-buffered) ----
// xs = bf16((x @ W1) * dinv[row]). Tile 64x256, BK=32, 4 waves x (4x4 16x16x32).
// LDS rows padded to 40 shorts. Reg-prefetch next K-chunk; 1 barrier/iter.

__global__ __launch_bounds__(256) void gemm1_kernel(const float* __restrict__ x,
                                                    const unsigned short* __restrict__ w1t,
                                                    const float* __restrict__ dinv,
                                                    unsigned short* __restrict__ xs, int M) {
    __shared__ unsigned short As[2][64 * 40];
    __shared__ unsigned short Bs[2][256 * 40];
    int t = threadIdx.x;
    int m0 = blockIdx.x * 64;
    int lane = t & 63, wv = t >> 6;
    int wn = wv * 64;
    int lm = lane & 15, q = lane >> 4;

    int ra = t >> 2, kc = (t & 3) * 8;
    int am = m0 + ra; if (am >= M) am = M - 1;
    const float* Ap = x + (size_t)am * 512 + kc;
    const unsigned short* Bp = w1t + (size_t)ra * 512 + kc;

    f32x4 acc[4][4];
    f32x4 z = {0.f, 0.f, 0.f, 0.f};
    #pragma unroll
    for (int i = 0; i < 4; i++)
        #pragma unroll
        for (int j = 0; j < 4; j++) acc[i][j] = z;

    // prologue: k=0 chunk
    float4 a0 = *(const float4*)(Ap + 0);
    float4 a1 = *(const float4*)(Ap + 4);
    uint4 b0 = *(const uint4*)(Bp + 0);
    uint4 b1 = *(const uint4*)(Bp + 64 * 512);
    uint4 b2 = *(const uint4*)(Bp + 128 * 512);
    uint4 b3 = *(const uint4*)(Bp + 192 * 512);
    {
        uint4 ap;
        ap.x = (unsigned int)f2bf(a0.x) | ((unsigned int)f2bf(a0.y) << 16);
        ap.y = (unsigned int)f2bf(a0.z) | ((unsigned int)f2bf(a0.w) << 16);
        ap.z = (unsigned int)f2bf(a1.x) | ((unsigned int)f2bf(a1.y) << 16);
        ap.w = (unsigned int)f2bf(a1.z) | ((unsigned int)f2bf(a1.w) << 16);
        *(uint4*)&As[0][ra * 40 + kc] = ap;
        *(uint4*)&Bs[0][(ra +   0) * 40 + kc] = b0;
        *(uint4*)&Bs[0][(ra +  64) * 40 + kc] = b1;
        *(uint4*)&Bs[0][(ra + 128) * 40 + kc] = b2;
        *(uint4*)&Bs[0][(ra + 192) * 40 + kc] = b3;
    }
    __syncthreads();

    int buf = 0;
    for (int k0 = 0; k0 < 512; k0 += 32) {
        bool more = (k0 + 32) < 512;
        if (more) {
            a0 = *(const float4*)(Ap + k0 + 32);
            a1 = *(const float4*)(Ap + k0 + 36);
            b0 = *(const uint4*)(Bp + k0 + 32);
            b1 = *(const uint4*)(Bp + k0 + 32 + 64 * 512);
            b2 = *(const uint4*)(Bp + k0 + 32 + 128 * 512);
            b3 = *(const uint4*)(Bp + k0 + 32 + 192 * 512);
        }
        short8 af[4], bfr[4];
        #pragma unroll
        for (int i = 0; i < 4; i++)
            af[i] = *(const short8*)&As[buf][(i * 16 + lm) * 40 + q * 8];
        #pragma unroll
        for (int j = 0; j < 4; j++)
            bfr[j] = *(const short8*)&Bs[buf][(wn + j * 16 + lm) * 40 + q * 8];
        #pragma unroll
        for (int i = 0; i < 4; i++)
            #pragma unroll
            for (int j = 0; j < 4; j++)
                acc[i][j] = __builtin_amdgcn_mfma_f32_16x16x32_bf16(af[i], bfr[j], acc[i][j], 0, 0, 0);
        if (more) {
            uint4 ap;
            ap.x = (unsigned int)f2bf(a0.x) | ((unsigned int)f2bf(a0.y) << 16);
            ap.y = (unsigned int)f2bf(a0.z) | ((unsigned int)f2bf(a0.w) << 16);
            ap.z = (unsigned int)f2bf(a1.x) | ((unsigned int)f2bf(a1.y) << 16);
            ap.w = (unsigned int)f2bf(a1.z) | ((unsigned int)f2bf(a1.w) << 16);
            int nb = buf ^ 1;
            *(uint4*)&As[nb][ra * 40 + kc] = ap;
            *(uint4*)&Bs[nb][(ra +   0) * 40 + kc] = b0;
            *(uint4*)&Bs[nb][(ra +  64) * 40 + kc] = b1;
            *(uint4*)&Bs[nb][(ra + 128) * 40 + kc] = b2;
            *(uint4*)&Bs[nb][(ra + 192) * 40 + kc] = b3;
            __syncthreads();
        }
        buf ^= 1;
    }

    #pragma unroll
    for (int i = 0; i < 4; i++) {
        #pragma unroll
        for (int r = 0; r < 4; r++) {
            int m = m0 + i * 16 + q * 4 + r;
            if (m < M) {
                float d = dinv[m];
                #pragma unroll
                for (int j = 0; j < 4; j++) {
                    int n = wn + j * 16 + lm;
                    xs[(size_t)m * 256 + n] = f2bf(acc[i][j][r] * d);
                }
            }
        }
    }
}

// ---------------- layer 1 aggregate ----------------
// One wave per column. Lane l covers features (l&31)*8..+7 via uint4 (16B);
// lanes 0-31 take even edges, lanes 32-63 odd edges -> one dwordx4 = 2 edge rows (1KB).
// Main loop: 8 edges / iter = 4KB in flight per wave. Parity merge: shfl_xor(.,32).

__global__ __launch_bounds__(256) void spmm1_kernel(const unsigned short* __restrict__ xs,
                                                    const int* __restrict__ colptr,
                                                    const int* __restrict__ eidx,
                                                    const float* __restrict__ dinv,
                                                    const float* __restrict__ b1,
                                                    unsigned short* __restrict__ h, int Nn) {
    int wid = threadIdx.x >> 6, lane = threadIdx.x & 63;
    int c = blockIdx.x * 4 + wid;
    if (c >= Nn) return;
    int half = lane >> 5;        // edge parity this lane handles
    int fl = lane & 31;          // feature block: features fl*8 .. fl*8+7
    const uint4* xb = (const uint4*)xs;    // row stride = 32 uint4

    uint4 sv = xb[(size_t)((unsigned)c * 32u + fl)];   // self row (in flight early)

    float a0 = 0.f, a1 = 0.f, a2 = 0.f, a3 = 0.f;
    float a4 = 0.f, a5 = 0.f, a6 = 0.f, a7 = 0.f;

    int j = colptr[c], jend = colptr[c + 1];

    for (; j + 8 <= jend; j += 8) {
        int r0 = eidx[j     + half];
        int r1 = eidx[j + 2 + half];
        int r2 = eidx[j + 4 + half];
        int r3 = eidx[j + 6 + half];
        uint4 v0 = xb[(size_t)((unsigned)r0 * 32u + fl)];
        uint4 v1 = xb[(size_t)((unsigned)r1 * 32u + fl)];
        uint4 v2 = xb[(size_t)((unsigned)r2 * 32u + fl)];
        uint4 v3 = xb[(size_t)((unsigned)r3 * 32u + fl)];
        a0 += (blo(v0.x) + blo(v1.x)) + (blo(v2.x) + blo(v3.x));
        a1 += (bhi(v0.x) + bhi(v1.x)) + (bhi(v2.x) + bhi(v3.x));
        a2 += (blo(v0.y) + blo(v1.y)) + (blo(v2.y) + blo(v3.y));
        a3 += (bhi(v0.y) + bhi(v1.y)) + (bhi(v2.y) + bhi(v3.y));
        a4 += (blo(v0.z) + blo(v1.z)) + (blo(v2.z) + blo(v3.z));
        a5 += (bhi(v0.z) + bhi(v1.z)) + (bhi(v2.z) + bhi(v3.z));
        a6 += (blo(v0.w) + blo(v1.w)) + (blo(v2.w) + blo(v3.w));
        a7 += (bhi(v0.w) + bhi(v1.w)) + (bhi(v2.w) + bhi(v3.w));
    }
    for (; j < jend; j += 2) {
        int e = j + half;
        bool ok = e < jend;
        int r = eidx[ok ? e : (jend - 1)];
        float m = ok ? 1.f : 0.f;
        uint4 v = xb[(size_t)((unsigned)r * 32u + fl)];
        a0 = fmaf(m, blo(v.x), a0);
        a1 = fmaf(m, bhi(v.x), a1);
        a2 = fmaf(m, blo(v.y), a2);
        a3 = fmaf(m, bhi(v.y), a3);
        a4 = fmaf(m, blo(v.z), a4);
        a5 = fmaf(m, bhi(v.z), a5);
        a6 = fmaf(m, blo(v.w), a6);
        a7 = fmaf(m, bhi(v.w), a7);
    }

    // merge parity halves (lane and lane^32 hold same features, different edges)
    a0 += __shfl_xor(a0, 32);
    a1 += __shfl_xor(a1, 32);
    a2 += __shfl_xor(a2, 32);
    a3 += __shfl_xor(a3, 32);
    a4 += __shfl_xor(a4, 32);
    a5 += __shfl_xor(a5, 32);
    a6 += __shfl_xor(a6, 32);
    a7 += __shfl_xor(a7, 32);

    // self contribution (identical in both halves)
    a0 += blo(sv.x); a1 += bhi(sv.x);
    a2 += blo(sv.y); a3 += bhi(sv.y);
    a4 += blo(sv.z); a5 += bhi(sv.z);
    a6 += blo(sv.w); a7 += bhi(sv.w);

    float d = dinv[c];
    float4 bb0 = ((const float4*)b1)[fl * 2];
    float4 bb1 = ((const float4*)b1)[fl * 2 + 1];
    float f0 = fmaxf(a0 * d + bb0.x, 0.f);
    float f1 = fmaxf(a1 * d + bb0.y, 0.f);
    float f2 = fmaxf(a2 * d + bb0.z, 0.f);
    float f3 = fmaxf(a3 * d + bb0.w, 0.f);
    float f4 = fmaxf(a4 * d + bb1.x, 0.f);
    float f5 = fmaxf(a5 * d + bb1.y, 0.f);
    float f6 = fmaxf(a6 * d + bb1.z, 0.f);
    float f7 = fmaxf(a7 * d + bb1.w, 0.f);
    uint4 p;
    p.x = (unsigned int)f2bf(f0) | ((unsigned int)f2bf(f1) << 16);
    p.y = (unsigned int)f2bf(f2) | ((unsigned int)f2bf(f3) << 16);
    p.z = (unsigned int)f2bf(f4) | ((unsigned int)f2bf(f5) << 16);
    p.w = (unsigned int)f2bf(f6) | ((unsigned int)f2bf(f7) << 16);
    if (lane < 32)
        *(uint4*)(h + (size_t)c * 256 + fl * 8) = p;
}

// ---------------- layer 2 GEMM (bf16 MFMA): t2p = bf16((h @ W2) * dinv), stride 64 --

__global__ __launch_bounds__(256) void gemm2_kernel(const unsigned short* __restrict__ h,
                                                    const unsigned short* __restrict__ w2t,
                                                    const float* __restrict__ dinv,
                                                    unsigned short* __restrict__ t2p, int M) {
    __shared__ unsigned short As[64 * 264];
    __shared__ unsigned short Bs[64 * 264];
    int t = threadIdx.x;
    int m0 = blockIdx.x * 64;
    int lane = t & 63, wv = t >> 6;
    int lm = lane & 15, q = lane >> 4;

    #pragma unroll
    for (int i = 0; i < 8; i++) {
        int c = t + i * 256;
        int row = c >> 5, col = (c & 31) * 8;
        int m = m0 + row; if (m >= M) m = M - 1;
        uint4 av = *(const uint4*)(h + (size_t)m * 256 + col);
        *(uint4*)&As[row * 264 + col] = av;
        uint4 bv = *(const uint4*)(w2t + (size_t)row * 256 + col);
        *(uint4*)&Bs[row * 264 + col] = bv;
    }
    __syncthreads();

    f32x4 acc[4];
    f32x4 z = {0.f, 0.f, 0.f, 0.f};
    #pragma unroll
    for (int j = 0; j < 4; j++) acc[j] = z;

    #pragma unroll
    for (int k0 = 0; k0 < 256; k0 += 32) {
        short8 af = *(const short8*)&As[(wv * 16 + lm) * 264 + k0 + q * 8];
        #pragma unroll
        for (int j = 0; j < 4; j++) {
            short8 bf = *(const short8*)&Bs[(j * 16 + lm) * 264 + k0 + q * 8];
            acc[j] = __builtin_amdgcn_mfma_f32_16x16x32_bf16(af, bf, acc[j], 0, 0, 0);
        }
    }

    #pragma unroll
    for (int r = 0; r < 4; r++) {
        int m = m0 + wv * 16 + q * 4 + r;
        if (m < M) {
            float d = dinv[m];
            #pragma unroll
            for (int j = 0; j < 4; j++)
                t2p[(size_t)m * 64 + j * 16 + lm] = f2bf(acc[j][r] * d);
        }
    }
}

// ---------------- layer 2 aggregate + bias + log_softmax ----------------
// Lane l covers features (l&15)*4..+3 via uint2 (8B); group g=l>>4 takes edge j+g
// -> one dwordx2 = 4 edge rows (512B). Unroll x2 = 8 edges in flight.

__global__ __launch_bounds__(256) void spmm2_kernel(const unsigned short* __restrict__ t2p,
                                                    const int* __restrict__ colptr,
                                                    const int* __restrict__ eidx,
                                                    const float* __restrict__ dinv,
                                                    const float* __restrict__ b2,
                                                    float* __restrict__ out, int Nn) {
    int wid = threadIdx.x >> 6, lane = threadIdx.x & 63;
    int c = blockIdx.x * 4 + wid;
    if (c >= Nn) return;
    int g = lane >> 4;           // edge slot within 4-pack
    int fl = lane & 15;          // feature block: features fl*4 .. fl*4+3
    const uint2* tb = (const uint2*)t2p;   // row stride = 16 uint2

    uint2 sv = tb[(size_t)((unsigned)c * 16u + fl)];

    float a0 = 0.f, a1 = 0.f, a2 = 0.f, a3 = 0.f;
    int j = colptr[c], jend = colptr[c + 1];

    for (; j + 8 <= jend; j += 8) {
        int r0 = eidx[j     + g];
        int r1 = eidx[j + 4 + g];
        uint2 v0 = tb[(size_t)((unsigned)r0 * 16u + fl)];
        uint2 v1 = tb[(size_t)((unsigned)r1 * 16u + fl)];
        a0 += blo(v0.x) + blo(v1.x);
        a1 += bhi(v0.x) + bhi(v1.x);
        a2 += blo(v0.y) + blo(v1.y);
        a3 += bhi(v0.y) + bhi(v1.y);
    }
    for (; j < jend; j += 4) {
        int e = j + g;
        bool ok = e < jend;
        int r = eidx[ok ? e : (jend - 1)];
        float m = ok ? 1.f : 0.f;
        uint2 v = tb[(size_t)((unsigned)r * 16u + fl)];
        a0 = fmaf(m, blo(v.x), a0);
        a1 = fmaf(m, bhi(v.x), a1);
        a2 = fmaf(m, blo(v.y), a2);
        a3 = fmaf(m, bhi(v.y), a3);
    }

    // merge 4 edge groups: fold over lanes 16 and 32 apart
    a0 += __shfl_xor(a0, 16); a0 += __shfl_xor(a0, 32);
    a1 += __shfl_xor(a1, 16); a1 += __shfl_xor(a1, 32);
    a2 += __shfl_xor(a2, 16); a2 += __shfl_xor(a2, 32);
    a3 += __shfl_xor(a3, 16); a3 += __shfl_xor(a3, 32);

    // self contribution (identical in all groups)
    a0 += blo(sv.x); a1 += bhi(sv.x);
    a2 += blo(sv.y); a3 += bhi(sv.y);

    float d = dinv[c];
    bool valid = fl < 10;                       // features fl*4..+3 < 40
    float4 bb = {0.f, 0.f, 0.f, 0.f};
    if (valid) bb = ((const float4*)b2)[fl];
    float v0 = valid ? (a0 * d + bb.x) : -INFINITY;
    float v1 = valid ? (a1 * d + bb.y) : -INFINITY;
    float v2 = valid ? (a2 * d + bb.z) : -INFINITY;
    float v3 = valid ? (a3 * d + bb.w) : -INFINITY;

    float mx = fmaxf(fmaxf(v0, v1), fmaxf(v2, v3));
    #pragma unroll
    for (int o = 8; o > 0; o >>= 1) { float z = __shfl_xor(mx, o); mx = fmaxf(mx, z); }
    float ex = valid ? (expf(v0 - mx) + expf(v1 - mx) + expf(v2 - mx) + expf(v3 - mx)) : 0.f;
    #pragma unroll
    for (int o = 8; o > 0; o >>= 1) ex += __shfl_xor(ex, o);
    float ls = logf(ex);

    if (lane < 10) {
        float4 o4;
        o4.x = v0 - mx - ls;
        o4.y = v1 - mx - ls;
        o4.z = v2 - mx - ls;
        o4.w = v3 - mx - ls;
        *(float4*)(out + (size_t)c * 40 + fl * 4) = o4;
    }
}

// ---------------- launcher ----------------

extern "C" void kernel_launch(void* const* d_in, const int* in_sizes, int n_in,
                              void* d_out, int out_size, void* d_ws, size_t ws_size,
                              hipStream_t stream) {
    const float* x  = (const float*)d_in[0];
    const int*   ei = (const int*)d_in[1];
    const float* W1 = (const float*)d_in[2];
    const float* b1 = (const float*)d_in[3];
    const float* W2 = (const float*)d_in[4];
    const float* b2 = (const float*)d_in[5];
    float* out = (float*)d_out;

    int N = in_sizes[0] / 512;   // 100000
    int E = in_sizes[1] / 2;     // 3200000

    char* p = (char*)d_ws;
    auto carve = [&](size_t bytes) -> char* {
        char* q = p;
        p += (bytes + 1023) & ~(size_t)1023;
        return q;
    };
    float* dinv   = (float*)carve((size_t)N * 4);
    int*   cnt    = (int*)carve((size_t)N * 4);
    int*   colptr = (int*)carve(((size_t)N + 1) * 4);
    int*   fillc  = (int*)carve((size_t)N * 4);
    int*   bsum   = (int*)carve(1024 * 4);
    int*   eidx   = (int*)carve((size_t)E * 4);
    unsigned short* w1t = (unsigned short*)carve((size_t)256 * 512 * 2);
    unsigned short* w2t = (unsigned short*)carve((size_t)64 * 256 * 2);
    unsigned short* xs  = (unsigned short*)carve((size_t)N * 256 * 2);
    unsigned short* h   = (unsigned short*)carve((size_t)N * 256 * 2);
    unsigned short* t2p = (unsigned short*)carve((size_t)N * 64 * 2);

    hipMemsetAsync(cnt,   0, (size_t)N * 4, stream);
    hipMemsetAsync(fillc, 0, (size_t)N * 4, stream);

    int eb = (E + 255) / 256;
    int nb = (N + 511) / 512;

    count_kernel<<<eb, 256, 0, stream>>>(ei, cnt, E);
    scanA_kernel<<<nb, 256, 0, stream>>>(cnt, dinv, colptr, bsum, N);
    scanB_kernel<<<1, 256, 0, stream>>>(bsum, nb);
    scanC_kernel<<<nb, 256, 0, stream>>>(colptr, bsum, N, E);
    fill_kernel<<<eb, 256, 0, stream>>>(ei, colptr, fillc, eidx, E);
    prep_w_kernel<<<576, 256, 0, stream>>>(W1, W2, w1t, w2t);

    int mb = (N + 63) / 64;
    gemm1_kernel<<<mb, 256, 0, stream>>>(x, w1t, dinv, xs, N);
    spmm1_kernel<<<(N + 3) / 4, 256, 0, stream>>>(xs, colptr, eidx, dinv, b1, h, N);
    gemm2_kernel<<<mb, 256, 0, stream>>>(h, w2t, dinv, t2p, N);
    spmm2_kernel<<<(N + 3) / 4, 256, 0, stream>>>(t2p, colptr, eidx, dinv, b2, out, N);
}